// Round 11
// baseline (139.520 us; speedup 1.0000x reference)
//
#include <hip/hip_runtime.h>
#include <stdint.h>

// B=4, T=4096, C=256, H=64 non-causal attention. Scale=C^-0.5=1/16 folded
// (with log2e) into Q. exp2-domain softmax throughout.
#define QK_SCALE 0.09016844005555021f   // log2(e) / 16

typedef short short8 __attribute__((ext_vector_type(8)));
typedef float f32x4 __attribute__((ext_vector_type(4)));

static __device__ __forceinline__ unsigned short f2bf(float f){
  unsigned u = __builtin_bit_cast(unsigned, f);
  u += 0x7fffu + ((u >> 16) & 1u);           // RNE
  return (unsigned short)(u >> 16);
}
static __device__ __forceinline__ float fexp2(float x){
  float r; asm("v_exp_f32 %0, %1" : "=v"(r) : "v"(x)); return r;
}
static __device__ __forceinline__ unsigned cvtpk(float lo, float hi){
  unsigned r; asm("v_cvt_pk_bf16_f32 %0, %1, %2" : "=v"(r) : "v"(lo), "v"(hi));
  return r;
}

// ---------------- kernel 0: pack weights bf16 [j][ncol][k] ------------------
__global__ __launch_bounds__(256) void pack_w_k(const float* __restrict__ Wk,
    const float* __restrict__ Wq, const float* __restrict__ Wv,
    unsigned short* __restrict__ wt){
  int j = blockIdx.x >> 6;            // 0:K 1:Q 2:V
  int n = blockIdx.x & 63;
  int k = threadIdx.x;                // 0..255
  const float* W = (j==0) ? Wk : ((j==1) ? Wq : Wv);
  float s = (j==1) ? QK_SCALE : 1.0f;
  wt[j*16384 + n*256 + k] = f2bf(W[k*64 + n] * s);
}

// ---------------- kernel 1: QKV projection, 16 rows/block, grid 1024 --------
__global__ __launch_bounds__(256) void qkv_proj_k(const float* __restrict__ x,
    const float* __restrict__ bk, const float* __restrict__ bq,
    const unsigned short* __restrict__ wt,
    unsigned short* __restrict__ qw, unsigned short* __restrict__ kw,
    unsigned short* __restrict__ vtw){
  __shared__ __align__(16) unsigned char xl[8192];    // [16][256] bf16 swizzled
  __shared__ __align__(16) unsigned short vb[16*72];  // V bounce [t][d], ld=72
  const int tid = threadIdx.x;
  const int r0 = blockIdx.x << 4;

  #pragma unroll
  for (int i=0;i<4;++i){
    int f4 = tid + (i<<8);                       // 0..1023 float4 of tile
    float4 v = ((const float4*)x)[((size_t)r0<<6) + f4];
    int row = f4 >> 6;
    int byt = ((row<<9) + ((f4&63)<<3)) ^ ((row&7)<<4);
    uint2 pk; pk.x = cvtpk(v.x, v.y); pk.y = cvtpk(v.z, v.w);
    *(uint2*)(xl + byt) = pk;
  }
  __syncthreads();

  const int l = tid & 63, w = tid >> 6, g = l >> 4, c = l & 15;
  const int jn0 = w * 3;
  f32x4 acc[3];
  #pragma unroll
  for (int i=0;i<3;++i) acc[i] = (f32x4){0.f,0.f,0.f,0.f};

  #pragma unroll
  for (int kk=0;kk<8;++kk){
    short8 a = *(const short8*)(xl + (((c<<9) + (kk<<6) + (g<<4)) ^ ((c&7)<<4)));
    #pragma unroll
    for (int u=0;u<3;++u){
      int jn = jn0 + u, j = jn>>2, n = jn&3;
      short8 bf = *(const short8*)(wt + (size_t)j*16384 + (((n<<4)+c)<<8) + (kk<<5) + (g<<3));
      acc[u] = __builtin_amdgcn_mfma_f32_16x16x32_bf16(a, bf, acc[u], 0, 0, 0);
    }
  }

  #pragma unroll
  for (int u=0;u<3;++u){
    int jn = jn0 + u, j = jn>>2, n = jn&3;
    if (j == 0){
      float bK = bk[(n<<4)+c];
      #pragma unroll
      for (int r=0;r<4;++r)
        kw[((size_t)(r0 + (g<<2) + r)<<6) + (n<<4) + c] = f2bf(acc[u][r] + bK);
    } else if (j == 1){
      float bQ = bq[(n<<4)+c] * QK_SCALE;
      #pragma unroll
      for (int r=0;r<4;++r)
        qw[((size_t)(r0 + (g<<2) + r)<<6) + (n<<4) + c] = f2bf(acc[u][r] + bQ);
    } else {
      #pragma unroll
      for (int r=0;r<4;++r)
        vb[((g<<2)+r)*72 + (n<<4) + c] = f2bf(acc[u][r]);
    }
  }
  __syncthreads();
  // transpose out: vtw[b*64+d][t]; thread: d = tid>>2, 4 t-values
  int d = tid >> 2, tq = (tid & 3) << 2;
  unsigned s0 = vb[(tq+0)*72 + d], s1 = vb[(tq+1)*72 + d];
  unsigned s2 = vb[(tq+2)*72 + d], s3 = vb[(tq+3)*72 + d];
  uint2 pk; pk.x = s0 | (s1<<16); pk.y = s2 | (s3<<16);
  int b = r0 >> 12, t0 = r0 & 4095;
  *(uint2*)(vtw + (((size_t)(b<<6) + d)<<12) + t0 + tq) = pk;
}

// ---------------- kernel 2: flash attention (swapped QK^T), partials only ---
// grid 512 linear: bid&7 = split (XCD-pinned: round-robin dispatch puts each
// split's blocks on one XCD -> its 256KB K/V slice stays L2-hot), bid>>3 = qb.
// Block = 256 q-rows, 4 waves x 64 q (MT=4): K/V LDS reads shared across 4 mt
// -> LDS read amplification 2x (was 4x at MT=2), barriers per q halved.
// S^T = mfma(K, Q): lane owns q = lane&15 (+16*mt); softmax lane-local.
// Key bijection kphys = 16*(2*kk+(j>>2)) + 4*g + (j&3)  <->  kslot = 32*kk+8*g+j
// makes P^T -> B-frag repack pure cvt_pk (no cross-lane). V^T staged with the
// matching column permute. LDS: K dbuf 2x8KB + V dbuf 2x8KB, XOR-swizzled.
// NOTE R5/R8: do NOT set launch_bounds min-waves (arg=4 -> 64 VGPR, arg=2 ->
// 88 VGPR, both spill ~40+ regs -> 168-192us). Bare (256) lets RA breathe.
__global__ __launch_bounds__(256) void attn_k(
    const unsigned short* __restrict__ qw, const unsigned short* __restrict__ kw,
    const unsigned short* __restrict__ vtw,
    float* __restrict__ opart, float* __restrict__ mpart, float* __restrict__ lpart){
  __shared__ __align__(16) unsigned char kl[16384];
  __shared__ __align__(16) unsigned char vl[16384];
  const int tid = threadIdx.x;
  const int l = tid & 63, w = tid >> 6, g = l >> 4, c = l & 15;
  const int bid = blockIdx.x;
  const int split = bid & 7, qb = bid >> 3;   // qb 0..63
  const int b = qb >> 4, tq0 = (qb & 15) << 8;
  const int kt0 = split << 3;                 // 8 tiles of 64 keys per split
  const int qrow0 = (b<<12) + tq0 + (w<<6);   // wave's 64-q base row

  // Q B-frags (col q = c, contraction e = kk*32 + g*8 + j)
  short8 qa[4][2];
  #pragma unroll
  for (int mt=0;mt<4;++mt)
    #pragma unroll
    for (int kk=0;kk<2;++kk)
      qa[mt][kk] = *(const short8*)(qw +
        ((size_t)(qrow0 + (mt<<4) + c)<<6) + (kk<<5) + (g<<3));

  f32x4 o[4][4];
  float mrow[4] = {-1e30f,-1e30f,-1e30f,-1e30f}, lrow[4] = {0.f,0.f,0.f,0.f};
  #pragma unroll
  for (int mt=0;mt<4;++mt)
    #pragma unroll
    for (int df=0;df<4;++df) o[mt][df] = (f32x4){0.f,0.f,0.f,0.f};

  const int srow = tid >> 3;                  // 0..31 (+32 on 2nd half)
  const int scol = tid & 7;                   // 16B unit / kphys-octet h
  const int offA = ((scol>>2)<<6) + ((scol&1)<<5) + (((scol>>1)&1)<<3);
  const int offB = offA + 16;                 // permuted V dest offsets (bytes)

  uint4 rk[2], rv[2];
  #define LOADT(kt) { \
    _Pragma("unroll") \
    for (int u=0;u<2;++u){ \
      int row = srow + (u<<5); \
      rk[u] = *(const uint4*)(kw + ((size_t)((b<<12) + ((kt)<<6) + row)<<6) + (scol<<3)); \
      rv[u] = *(const uint4*)(vtw + (((size_t)((b<<6) + row))<<12) + ((kt)<<6) + (scol<<3)); \
    } }
  #define STORET(buf) { \
    _Pragma("unroll") \
    for (int u=0;u<2;++u){ \
      int row = srow + (u<<5); \
      *(uint4*)(kl + ((buf)<<13) + (((row<<7)+(scol<<4)) ^ ((row&7)<<4))) = rk[u]; \
      unsigned char* vbase = vl + ((buf)<<13) + (row<<7); \
      int sz = (row&7)<<4; \
      uint2 t0_; t0_.x = rv[u].x; t0_.y = rv[u].y; \
      uint2 t1_; t1_.x = rv[u].z; t1_.y = rv[u].w; \
      *(uint2*)(vbase + (offA ^ sz)) = t0_; \
      *(uint2*)(vbase + (offB ^ sz)) = t1_; \
    } }

  LOADT(kt0); STORET(0);
  __syncthreads();

  for (int it=0; it<8; ++it){
    const int buf = it & 1;
    if (it < 7) LOADT(kt0 + it + 1);
    const unsigned char* kb_ = kl + (buf<<13);
    const unsigned char* vb_ = vl + (buf<<13);

    // --- QK^T: S^T[key][q] ---
    f32x4 s[4][4];
    #pragma unroll
    for (int mt=0;mt<4;++mt)
      #pragma unroll
      for (int n=0;n<4;++n) s[mt][n] = (f32x4){0.f,0.f,0.f,0.f};
    __builtin_amdgcn_s_setprio(1);
    #pragma unroll
    for (int kk=0;kk<2;++kk){
      #pragma unroll
      for (int n=0;n<4;++n){
        int rowk = (n<<4) + c;
        short8 ka = *(const short8*)(kb_ + (((rowk<<7) + (kk<<6) + (g<<4)) ^ ((rowk&7)<<4)));
        #pragma unroll
        for (int mt=0;mt<4;++mt)
          s[mt][n] = __builtin_amdgcn_mfma_f32_16x16x32_bf16(ka, qa[mt][kk], s[mt][n], 0,0,0);
      }
    }
    __builtin_amdgcn_s_setprio(0);

    // --- softmax max phase (lane-local, exp2 domain, defer-max THR=8) ---
    #pragma unroll
    for (int mt=0;mt<4;++mt){
      float a0 = fmaxf(fmaxf(s[mt][0][0], s[mt][0][1]), fmaxf(s[mt][0][2], s[mt][0][3]));
      float a1 = fmaxf(fmaxf(s[mt][1][0], s[mt][1][1]), fmaxf(s[mt][1][2], s[mt][1][3]));
      float a2 = fmaxf(fmaxf(s[mt][2][0], s[mt][2][1]), fmaxf(s[mt][2][2], s[mt][2][3]));
      float a3 = fmaxf(fmaxf(s[mt][3][0], s[mt][3][1]), fmaxf(s[mt][3][2], s[mt][3][3]));
      float t0 = fmaxf(fmaxf(a0,a1), fmaxf(a2,a3));
      t0 = fmaxf(t0, __shfl_xor(t0, 16));
      t0 = fmaxf(t0, __shfl_xor(t0, 32));
      float mo = mrow[mt];
      if (!__all(t0 <= mo + 8.f)){
        float mn = fmaxf(mo, t0);
        float al = fexp2(mo - mn);
        mrow[mt] = mn; lrow[mt] *= al;
        #pragma unroll
        for (int df=0;df<4;++df){
          o[mt][df][0]*=al; o[mt][df][1]*=al; o[mt][df][2]*=al; o[mt][df][3]*=al;
        }
      }
    }

    // --- per-kk: exp slice + pack P^T + PV (caps pb liveness) ---
    #pragma unroll
    for (int kk=0;kk<2;++kk){
      short8 pb[4];
      #pragma unroll
      for (int mt=0;mt<4;++mt){
        float m = mrow[mt];
        #pragma unroll
        for (int n=2*kk;n<2*kk+2;++n)
          #pragma unroll
          for (int r=0;r<4;++r) s[mt][n][r] = fexp2(s[mt][n][r] - m);
        float p0 = (s[mt][2*kk][0]+s[mt][2*kk][1]) + (s[mt][2*kk][2]+s[mt][2*kk][3]);
        float p1 = (s[mt][2*kk+1][0]+s[mt][2*kk+1][1]) + (s[mt][2*kk+1][2]+s[mt][2*kk+1][3]);
        lrow[mt] += p0 + p1;
        uint4 pw;
        pw.x = cvtpk(s[mt][2*kk][0],   s[mt][2*kk][1]);
        pw.y = cvtpk(s[mt][2*kk][2],   s[mt][2*kk][3]);
        pw.z = cvtpk(s[mt][2*kk+1][0], s[mt][2*kk+1][1]);
        pw.w = cvtpk(s[mt][2*kk+1][2], s[mt][2*kk+1][3]);
        pb[mt] = __builtin_bit_cast(short8, pw);
      }
      __builtin_amdgcn_s_setprio(1);
      #pragma unroll
      for (int df=0;df<4;++df){
        int rowd = (df<<4) + c;
        short8 va = *(const short8*)(vb_ + (((rowd<<7) + (kk<<6) + (g<<4)) ^ ((rowd&7)<<4)));
        #pragma unroll
        for (int mt=0;mt<4;++mt)
          o[mt][df] = __builtin_amdgcn_mfma_f32_16x16x32_bf16(va, pb[mt], o[mt][df], 0,0,0);
      }
      __builtin_amdgcn_s_setprio(0);
    }

    if (it < 7) STORET(buf^1);
    __syncthreads();
  }

  // --- epilogue: partials (unnormalized O^T, m, l) ---
  #pragma unroll
  for (int mt=0;mt<4;++mt){
    float ls = lrow[mt];
    ls += __shfl_xor(ls, 16);
    ls += __shfl_xor(ls, 32);
    int grow = qrow0 + (mt<<4) + c;
    if (l < 16){
      mpart[(split<<14) + grow] = mrow[mt];
      lpart[(split<<14) + grow] = ls;
    }
    #pragma unroll
    for (int df=0;df<4;++df)
      *(f32x4*)(opart + ((size_t)split<<20) + ((size_t)grow<<6) + (df<<4) + (g<<2)) = o[mt][df];
  }
}

// ---------------- kernel 3: combine the 8 key-splits (vectorized) -----------
__global__ __launch_bounds__(256) void combine_k(const float* __restrict__ opart,
    const float* __restrict__ mpart, const float* __restrict__ lpart,
    float* __restrict__ out){
  int idx4 = blockIdx.x*256 + threadIdx.x;      // 0 .. 262143 (f32x4 units)
  int row = idx4 >> 4;
  float mm = -1e30f;
  #pragma unroll
  for (int sp=0;sp<8;++sp) mm = fmaxf(mm, mpart[(sp<<14) + row]);
  f32x4 num = (f32x4){0.f,0.f,0.f,0.f};
  float den = 0.f;
  #pragma unroll
  for (int sp=0;sp<8;++sp){
    float a = fexp2(mpart[(sp<<14) + row] - mm);
    den += lpart[(sp<<14) + row] * a;
    f32x4 v = *(const f32x4*)(opart + ((size_t)sp<<20) + ((size_t)idx4<<2));
    num[0]+=v[0]*a; num[1]+=v[1]*a; num[2]+=v[2]*a; num[3]+=v[3]*a;
  }
  float inv = 1.0f / den;
  f32x4 r; r[0]=num[0]*inv; r[1]=num[1]*inv; r[2]=num[2]*inv; r[3]=num[3]*inv;
  *(f32x4*)(out + ((size_t)idx4<<2)) = r;
}

extern "C" void kernel_launch(void* const* d_in, const int* in_sizes, int n_in,
                              void* d_out, int out_size, void* d_ws, size_t ws_size,
                              hipStream_t stream){
  const float* x  = (const float*)d_in[0];
  const float* Wk = (const float*)d_in[1];
  const float* bk = (const float*)d_in[2];
  const float* Wq = (const float*)d_in[3];
  const float* bq = (const float*)d_in[4];
  const float* Wv = (const float*)d_in[5];
  unsigned char* ws = (unsigned char*)d_ws;
  // ws: wt(96K)+pad | qw 2M | kw 2M | vtw 2M | opart 32M | mpart .5M | lpart .5M
  unsigned short* wt  = (unsigned short*)(ws);
  unsigned short* qw  = (unsigned short*)(ws + 131072);
  unsigned short* kw  = (unsigned short*)(ws + 131072 + 2097152);
  unsigned short* vtw = (unsigned short*)(ws + 131072 + 2u*2097152);
  const size_t base = 131072 + 3u*2097152;
  float* opart = (float*)(ws + base);
  float* mpart = (float*)(ws + base + 8u*4194304u);
  float* lpart = (float*)(ws + base + 8u*4194304u + 524288u);
  float* out = (float*)d_out;

  hipLaunchKernelGGL(pack_w_k,   dim3(192),  dim3(256), 0, stream, Wk, Wq, Wv, wt);
  hipLaunchKernelGGL(qkv_proj_k, dim3(1024), dim3(256), 0, stream, x, bk, bq, wt, qw, kw, vtw);
  hipLaunchKernelGGL(attn_k,     dim3(512),  dim3(256), 0, stream, qw, kw, vtw, opart, mpart, lpart);
  hipLaunchKernelGGL(combine_k,  dim3(1024), dim3(256), 0, stream, opart, mpart, lpart, out);
}

// Round 13
// 126.202 us; speedup vs baseline: 1.1055x; 1.1055x over previous
//
#include <hip/hip_runtime.h>
#include <stdint.h>

// B=4, T=4096, C=256, H=64 non-causal attention. Scale=C^-0.5=1/16 folded
// (with log2e) into Q. exp2-domain softmax throughout.
#define QK_SCALE 0.09016844005555021f   // log2(e) / 16

typedef short short8 __attribute__((ext_vector_type(8)));
typedef float f32x4 __attribute__((ext_vector_type(4)));

static __device__ __forceinline__ unsigned short f2bf(float f){
  unsigned u = __builtin_bit_cast(unsigned, f);
  u += 0x7fffu + ((u >> 16) & 1u);           // RNE
  return (unsigned short)(u >> 16);
}
static __device__ __forceinline__ float fexp2(float x){
  float r; asm("v_exp_f32 %0, %1" : "=v"(r) : "v"(x)); return r;
}
static __device__ __forceinline__ unsigned cvtpk(float lo, float hi){
  unsigned r; asm("v_cvt_pk_bf16_f32 %0, %1, %2" : "=v"(r) : "v"(lo), "v"(hi));
  return r;
}

// ---------------- kernel 0: pack weights bf16 [j][ncol][k] ------------------
__global__ __launch_bounds__(256) void pack_w_k(const float* __restrict__ Wk,
    const float* __restrict__ Wq, const float* __restrict__ Wv,
    unsigned short* __restrict__ wt){
  int j = blockIdx.x >> 6;            // 0:K 1:Q 2:V
  int n = blockIdx.x & 63;
  int k = threadIdx.x;                // 0..255
  const float* W = (j==0) ? Wk : ((j==1) ? Wq : Wv);
  float s = (j==1) ? QK_SCALE : 1.0f;
  wt[j*16384 + n*256 + k] = f2bf(W[k*64 + n] * s);
}

// ---------------- kernel 1: QKV projection, 16 rows/block, grid 1024 --------
__global__ __launch_bounds__(256) void qkv_proj_k(const float* __restrict__ x,
    const float* __restrict__ bk, const float* __restrict__ bq,
    const unsigned short* __restrict__ wt,
    unsigned short* __restrict__ qw, unsigned short* __restrict__ kw,
    unsigned short* __restrict__ vtw){
  __shared__ __align__(16) unsigned char xl[8192];    // [16][256] bf16 swizzled
  __shared__ __align__(16) unsigned short vb[16*72];  // V bounce [t][d], ld=72
  const int tid = threadIdx.x;
  const int r0 = blockIdx.x << 4;

  #pragma unroll
  for (int i=0;i<4;++i){
    int f4 = tid + (i<<8);                       // 0..1023 float4 of tile
    float4 v = ((const float4*)x)[((size_t)r0<<6) + f4];
    int row = f4 >> 6;
    int byt = ((row<<9) + ((f4&63)<<3)) ^ ((row&7)<<4);
    uint2 pk; pk.x = cvtpk(v.x, v.y); pk.y = cvtpk(v.z, v.w);
    *(uint2*)(xl + byt) = pk;
  }
  __syncthreads();

  const int l = tid & 63, w = tid >> 6, g = l >> 4, c = l & 15;
  const int jn0 = w * 3;
  f32x4 acc[3];
  #pragma unroll
  for (int i=0;i<3;++i) acc[i] = (f32x4){0.f,0.f,0.f,0.f};

  #pragma unroll
  for (int kk=0;kk<8;++kk){
    short8 a = *(const short8*)(xl + (((c<<9) + (kk<<6) + (g<<4)) ^ ((c&7)<<4)));
    #pragma unroll
    for (int u=0;u<3;++u){
      int jn = jn0 + u, j = jn>>2, n = jn&3;
      short8 bf = *(const short8*)(wt + (size_t)j*16384 + (((n<<4)+c)<<8) + (kk<<5) + (g<<3));
      acc[u] = __builtin_amdgcn_mfma_f32_16x16x32_bf16(a, bf, acc[u], 0, 0, 0);
    }
  }

  #pragma unroll
  for (int u=0;u<3;++u){
    int jn = jn0 + u, j = jn>>2, n = jn&3;
    if (j == 0){
      float bK = bk[(n<<4)+c];
      #pragma unroll
      for (int r=0;r<4;++r)
        kw[((size_t)(r0 + (g<<2) + r)<<6) + (n<<4) + c] = f2bf(acc[u][r] + bK);
    } else if (j == 1){
      float bQ = bq[(n<<4)+c] * QK_SCALE;
      #pragma unroll
      for (int r=0;r<4;++r)
        qw[((size_t)(r0 + (g<<2) + r)<<6) + (n<<4) + c] = f2bf(acc[u][r] + bQ);
    } else {
      #pragma unroll
      for (int r=0;r<4;++r)
        vb[((g<<2)+r)*72 + (n<<4) + c] = f2bf(acc[u][r]);
    }
  }
  __syncthreads();
  // transpose out: vtw[b*64+d][t]; thread: d = tid>>2, 4 t-values
  int d = tid >> 2, tq = (tid & 3) << 2;
  unsigned s0 = vb[(tq+0)*72 + d], s1 = vb[(tq+1)*72 + d];
  unsigned s2 = vb[(tq+2)*72 + d], s3 = vb[(tq+3)*72 + d];
  uint2 pk; pk.x = s0 | (s1<<16); pk.y = s2 | (s3<<16);
  int b = r0 >> 12, t0 = r0 & 4095;
  *(uint2*)(vtw + (((size_t)(b<<6) + d)<<12) + t0 + tq) = pk;
}

// ---------------- kernel 2: flash attention (swapped QK^T), partials only ---
// grid (128, 8): 128 q-blocks x 8 key-splits. 4 waves x 32 q-rows (MT=2).
// NOTE R11: MT=4 (grid 512, VGPR 164) HURT: 63us @ 9.9% occupancy — latency-
// chain-bound kernel, resident waves are the binding constraint. MT=2 keeps
// VGPR ~128 (occupancy cliff at 128, m69) and grid 1024 = 4 blocks/CU =
// 16 waves/CU, the ceiling for this register budget. Do NOT widen waves.
// S^T = mfma(K, Q): lane owns q = lane&15 (+16*mt); softmax lane-local.
// Key bijection kphys = 16*(2*kk+(j>>2)) + 4*g + (j&3)  <->  kslot = 32*kk+8*g+j
// makes P^T -> B-frag repack pure cvt_pk (no cross-lane). V^T staged with the
// matching column permute. LDS: K dbuf 2x8KB + V dbuf 2x8KB, XOR-swizzled.
// NOTE R5/R8: do NOT set launch_bounds min-waves (arg=4 -> 64 VGPR, arg=2 ->
// 88 VGPR, both spill ~40+ regs -> 168-192us). Bare (256) lets RA breathe.
__global__ __launch_bounds__(256) void attn_k(
    const unsigned short* __restrict__ qw, const unsigned short* __restrict__ kw,
    const unsigned short* __restrict__ vtw,
    float* __restrict__ opart, float* __restrict__ mpart, float* __restrict__ lpart){
  __shared__ __align__(16) unsigned char kl[16384];
  __shared__ __align__(16) unsigned char vl[16384];
  const int tid = threadIdx.x;
  const int l = tid & 63, w = tid >> 6, g = l >> 4, c = l & 15;
  const int qb = blockIdx.x, split = blockIdx.y;
  const int b = qb >> 5, tq0 = (qb & 31) << 7;
  const int kt0 = split << 3;                 // 8 tiles of 64 keys per split

  // Q B-frags (col q = c, contraction e = kk*32 + g*8 + j)
  short8 qa[2][2];
  #pragma unroll
  for (int mt=0;mt<2;++mt)
    #pragma unroll
    for (int kk=0;kk<2;++kk)
      qa[mt][kk] = *(const short8*)(qw +
        ((size_t)((b<<12) + tq0 + (w<<5) + (mt<<4) + c)<<6) + (kk<<5) + (g<<3));

  f32x4 o[2][4];
  float mrow[2] = {-1e30f, -1e30f}, lrow[2] = {0.f, 0.f};
  #pragma unroll
  for (int mt=0;mt<2;++mt)
    #pragma unroll
    for (int df=0;df<4;++df) o[mt][df] = (f32x4){0.f,0.f,0.f,0.f};

  const int srow = tid >> 3;                  // 0..31 (+32 on 2nd half)
  const int scol = tid & 7;                   // 16B unit / kphys-octet h
  const int offA = ((scol>>2)<<6) + ((scol&1)<<5) + (((scol>>1)&1)<<3);
  const int offB = offA + 16;                 // permuted V dest offsets (bytes)

  uint4 rk[2], rv[2];
  #define LOADT(kt) { \
    _Pragma("unroll") \
    for (int u=0;u<2;++u){ \
      int row = srow + (u<<5); \
      rk[u] = *(const uint4*)(kw + ((size_t)((b<<12) + ((kt)<<6) + row)<<6) + (scol<<3)); \
      rv[u] = *(const uint4*)(vtw + (((size_t)((b<<6) + row))<<12) + ((kt)<<6) + (scol<<3)); \
    } }
  #define STORET(buf) { \
    _Pragma("unroll") \
    for (int u=0;u<2;++u){ \
      int row = srow + (u<<5); \
      *(uint4*)(kl + ((buf)<<13) + (((row<<7)+(scol<<4)) ^ ((row&7)<<4))) = rk[u]; \
      unsigned char* vbase = vl + ((buf)<<13) + (row<<7); \
      int sz = (row&7)<<4; \
      uint2 t0_; t0_.x = rv[u].x; t0_.y = rv[u].y; \
      uint2 t1_; t1_.x = rv[u].z; t1_.y = rv[u].w; \
      *(uint2*)(vbase + (offA ^ sz)) = t0_; \
      *(uint2*)(vbase + (offB ^ sz)) = t1_; \
    } }

  LOADT(kt0); STORET(0);
  __syncthreads();

  for (int it=0; it<8; ++it){
    const int buf = it & 1;
    if (it < 7) LOADT(kt0 + it + 1);
    const unsigned char* kb_ = kl + (buf<<13);
    const unsigned char* vb_ = vl + (buf<<13);

    // --- QK^T: S^T[key][q] ---
    f32x4 s[2][4];
    #pragma unroll
    for (int mt=0;mt<2;++mt)
      #pragma unroll
      for (int n=0;n<4;++n) s[mt][n] = (f32x4){0.f,0.f,0.f,0.f};
    __builtin_amdgcn_s_setprio(1);
    #pragma unroll
    for (int kk=0;kk<2;++kk){
      #pragma unroll
      for (int n=0;n<4;++n){
        int rowk = (n<<4) + c;
        short8 ka = *(const short8*)(kb_ + (((rowk<<7) + (kk<<6) + (g<<4)) ^ ((rowk&7)<<4)));
        s[0][n] = __builtin_amdgcn_mfma_f32_16x16x32_bf16(ka, qa[0][kk], s[0][n], 0,0,0);
        s[1][n] = __builtin_amdgcn_mfma_f32_16x16x32_bf16(ka, qa[1][kk], s[1][n], 0,0,0);
      }
    }
    __builtin_amdgcn_s_setprio(0);

    // --- softmax (lane-local, exp2 domain, defer-max THR=8) + pack P^T ---
    short8 pb[2][2];
    #pragma unroll
    for (int mt=0;mt<2;++mt){
      float a0 = fmaxf(fmaxf(s[mt][0][0], s[mt][0][1]), fmaxf(s[mt][0][2], s[mt][0][3]));
      float a1 = fmaxf(fmaxf(s[mt][1][0], s[mt][1][1]), fmaxf(s[mt][1][2], s[mt][1][3]));
      float a2 = fmaxf(fmaxf(s[mt][2][0], s[mt][2][1]), fmaxf(s[mt][2][2], s[mt][2][3]));
      float a3 = fmaxf(fmaxf(s[mt][3][0], s[mt][3][1]), fmaxf(s[mt][3][2], s[mt][3][3]));
      float t0 = fmaxf(fmaxf(a0,a1), fmaxf(a2,a3));
      t0 = fmaxf(t0, __shfl_xor(t0, 16));
      t0 = fmaxf(t0, __shfl_xor(t0, 32));
      float mo = mrow[mt];
      if (!__all(t0 <= mo + 8.f)){
        float mn = fmaxf(mo, t0);
        float al = fexp2(mo - mn);
        mrow[mt] = mn; lrow[mt] *= al;
        #pragma unroll
        for (int df=0;df<4;++df){
          o[mt][df][0]*=al; o[mt][df][1]*=al; o[mt][df][2]*=al; o[mt][df][3]*=al;
        }
      }
      float m = mrow[mt];
      #pragma unroll
      for (int n=0;n<4;++n)
        #pragma unroll
        for (int r=0;r<4;++r) s[mt][n][r] = fexp2(s[mt][n][r] - m);
      float p0 = (s[mt][0][0]+s[mt][0][1]) + (s[mt][0][2]+s[mt][0][3]);
      float p1 = (s[mt][1][0]+s[mt][1][1]) + (s[mt][1][2]+s[mt][1][3]);
      float p2 = (s[mt][2][0]+s[mt][2][1]) + (s[mt][2][2]+s[mt][2][3]);
      float p3 = (s[mt][3][0]+s[mt][3][1]) + (s[mt][3][2]+s[mt][3][3]);
      lrow[mt] += (p0+p1) + (p2+p3);
      #pragma unroll
      for (int kk=0;kk<2;++kk){
        uint4 pw;
        pw.x = cvtpk(s[mt][2*kk][0],   s[mt][2*kk][1]);
        pw.y = cvtpk(s[mt][2*kk][2],   s[mt][2*kk][3]);
        pw.z = cvtpk(s[mt][2*kk+1][0], s[mt][2*kk+1][1]);
        pw.w = cvtpk(s[mt][2*kk+1][2], s[mt][2*kk+1][3]);
        pb[mt][kk] = __builtin_bit_cast(short8, pw);
      }
    }

    // --- PV: O^T += V^T(permuted) . P^T ---
    __builtin_amdgcn_s_setprio(1);
    #pragma unroll
    for (int kk=0;kk<2;++kk){
      #pragma unroll
      for (int df=0;df<4;++df){
        int rowd = (df<<4) + c;
        short8 va = *(const short8*)(vb_ + (((rowd<<7) + (kk<<6) + (g<<4)) ^ ((rowd&7)<<4)));
        o[0][df] = __builtin_amdgcn_mfma_f32_16x16x32_bf16(va, pb[0][kk], o[0][df], 0,0,0);
        o[1][df] = __builtin_amdgcn_mfma_f32_16x16x32_bf16(va, pb[1][kk], o[1][df], 0,0,0);
      }
    }
    __builtin_amdgcn_s_setprio(0);

    if (it < 7) STORET(buf^1);
    __syncthreads();
  }

  // --- epilogue: partials (unnormalized O^T, m, l) ---
  #pragma unroll
  for (int mt=0;mt<2;++mt){
    float ls = lrow[mt];
    ls += __shfl_xor(ls, 16);
    ls += __shfl_xor(ls, 32);
    int grow = (b<<12) + tq0 + (w<<5) + (mt<<4) + c;
    if (l < 16){
      mpart[(split<<14) + grow] = mrow[mt];
      lpart[(split<<14) + grow] = ls;
    }
    #pragma unroll
    for (int df=0;df<4;++df)
      *(f32x4*)(opart + ((size_t)split<<20) + ((size_t)grow<<6) + (df<<4) + (g<<2)) = o[mt][df];
  }
}

// ---------------- kernel 3: combine the 8 key-splits (vectorized) -----------
__global__ __launch_bounds__(256) void combine_k(const float* __restrict__ opart,
    const float* __restrict__ mpart, const float* __restrict__ lpart,
    float* __restrict__ out){
  int idx4 = blockIdx.x*256 + threadIdx.x;      // 0 .. 262143 (f32x4 units)
  int row = idx4 >> 4;
  float mm = -1e30f;
  #pragma unroll
  for (int sp=0;sp<8;++sp) mm = fmaxf(mm, mpart[(sp<<14) + row]);
  f32x4 num = (f32x4){0.f,0.f,0.f,0.f};
  float den = 0.f;
  #pragma unroll
  for (int sp=0;sp<8;++sp){
    float a = fexp2(mpart[(sp<<14) + row] - mm);
    den += lpart[(sp<<14) + row] * a;
    f32x4 v = *(const f32x4*)(opart + ((size_t)sp<<20) + ((size_t)idx4<<2));
    num[0]+=v[0]*a; num[1]+=v[1]*a; num[2]+=v[2]*a; num[3]+=v[3]*a;
  }
  float inv = 1.0f / den;
  f32x4 r; r[0]=num[0]*inv; r[1]=num[1]*inv; r[2]=num[2]*inv; r[3]=num[3]*inv;
  *(f32x4*)(out + ((size_t)idx4<<2)) = r;
}

extern "C" void kernel_launch(void* const* d_in, const int* in_sizes, int n_in,
                              void* d_out, int out_size, void* d_ws, size_t ws_size,
                              hipStream_t stream){
  const float* x  = (const float*)d_in[0];
  const float* Wk = (const float*)d_in[1];
  const float* bk = (const float*)d_in[2];
  const float* Wq = (const float*)d_in[3];
  const float* bq = (const float*)d_in[4];
  const float* Wv = (const float*)d_in[5];
  unsigned char* ws = (unsigned char*)d_ws;
  // ws: wt(96K)+pad | qw 2M | kw 2M | vtw 2M | opart 32M | mpart .5M | lpart .5M
  unsigned short* wt  = (unsigned short*)(ws);
  unsigned short* qw  = (unsigned short*)(ws + 131072);
  unsigned short* kw  = (unsigned short*)(ws + 131072 + 2097152);
  unsigned short* vtw = (unsigned short*)(ws + 131072 + 2u*2097152);
  const size_t base = 131072 + 3u*2097152;
  float* opart = (float*)(ws + base);
  float* mpart = (float*)(ws + base + 8u*4194304u);
  float* lpart = (float*)(ws + base + 8u*4194304u + 524288u);
  float* out = (float*)d_out;

  hipLaunchKernelGGL(pack_w_k,   dim3(192),    dim3(256), 0, stream, Wk, Wq, Wv, wt);
  hipLaunchKernelGGL(qkv_proj_k, dim3(1024),   dim3(256), 0, stream, x, bk, bq, wt, qw, kw, vtw);
  hipLaunchKernelGGL(attn_k,     dim3(128, 8), dim3(256), 0, stream, qw, kw, vtw, opart, mpart, lpart);
  hipLaunchKernelGGL(combine_k,  dim3(1024),   dim3(256), 0, stream, opart, mpart, lpart, out);
}